// Round 6
// baseline (777.338 us; speedup 1.0000x reference)
//
#include <hip/hip_runtime.h>
#include <math.h>
#include <stdint.h>

#define KG 64
#define KG3 (KG * KG * KG)
#define MZK 33  // Hermitian: mz in [0,32]
#define NBLK 512
#define NTHR 256
#define NWAVE (NBLK * 4)  // 2048 waves
#define DIB 256
#define DJT 32
#define ALPHA 0.34f
#define COULOMB 138.935456f
#define CUTOFF2 81.0f
#define PI_F 3.14159265358979323846f

// ---------------------------------------------------------------- helpers
struct BoxInfo {
    float inv[9];
    float vol;
    bool diag;
};
__device__ __forceinline__ BoxInfo load_box(const float* __restrict__ box) {
    BoxInfo b;
    float b0 = box[0], b1 = box[1], b2 = box[2];
    float b3 = box[3], b4 = box[4], b5 = box[5];
    float b6 = box[6], b7 = box[7], b8 = box[8];
    float det = b0 * (b4 * b8 - b5 * b7) - b1 * (b3 * b8 - b5 * b6) + b2 * (b3 * b7 - b4 * b6);
    float id = 1.0f / det;
    b.inv[0] = (b4 * b8 - b5 * b7) * id;
    b.inv[1] = (b2 * b7 - b1 * b8) * id;
    b.inv[2] = (b1 * b5 - b2 * b4) * id;
    b.inv[3] = (b5 * b6 - b3 * b8) * id;
    b.inv[4] = (b0 * b8 - b2 * b6) * id;
    b.inv[5] = (b2 * b3 - b0 * b5) * id;
    b.inv[6] = (b3 * b7 - b4 * b6) * id;
    b.inv[7] = (b1 * b6 - b0 * b7) * id;
    b.inv[8] = (b0 * b4 - b1 * b3) * id;
    b.vol = fabsf(det);
    b.diag = (b1 == 0.0f) && (b2 == 0.0f) && (b3 == 0.0f) && (b5 == 0.0f) && (b6 == 0.0f) &&
             (b7 == 0.0f);
    return b;
}

// fast erfc, Abramowitz-Stegun 7.1.26, |abs err| < 1.5e-7 for x >= 0
__device__ __forceinline__ float erfc_fast(float x) {
    float t = __builtin_amdgcn_rcpf(fmaf(0.3275911f, x, 1.0f));
    float p = fmaf(t, 1.061405429f, -1.453152027f);
    p = fmaf(t, p, 1.421413741f);
    p = fmaf(t, p, -0.284496736f);
    p = fmaf(t, p, 0.254829592f);
    return t * p * __expf(-x * x);
}

__device__ __forceinline__ void bspline4(float t, float* w) {
    float w0 = 1.0f - t, w1 = t;
    float a2 = 0.5f * t * w1;
    float a1 = 0.5f * ((t + 1.0f) * w0 + (2.0f - t) * w1);
    float a0 = 0.5f * (1.0f - t) * w0;
    const float d = 1.0f / 3.0f;
    w[3] = d * t * a2;
    w[2] = d * ((t + 1.0f) * a1 + (3.0f - t) * a2);
    w[1] = d * ((t + 2.0f) * a0 + (2.0f - t) * a1);
    w[0] = d * (1.0f - t) * a0;
}

__device__ __forceinline__ float sel4(const float* w, int j) {
    float r = w[0];
    r = (j == 1) ? w[1] : r;
    r = (j == 2) ? w[2] : r;
    r = (j == 3) ? w[3] : r;
    return r;
}

// ILP-8 twiddle chains
struct Tw8 {
    float wc[8], ws[8], c8, s8, c1, s1;
};
__device__ __forceinline__ Tw8 make_tw8(int m) {
    Tw8 T;
    float s1, c1;
    __sincosf(-2.0f * PI_F * (float)m / (float)KG, &s1, &c1);
    T.c1 = c1;
    T.s1 = s1;
    float c2 = c1 * c1 - s1 * s1, s2 = 2.0f * c1 * s1;
    float c4 = c2 * c2 - s2 * s2, s4 = 2.0f * c2 * s2;
    T.c8 = c4 * c4 - s4 * s4;
    T.s8 = 2.0f * c4 * s4;
    T.wc[0] = 1.0f;
    T.ws[0] = 0.0f;
    T.wc[1] = c1;
    T.ws[1] = s1;
    T.wc[2] = c2;
    T.ws[2] = s2;
    T.wc[3] = c2 * c1 - s2 * s1;
    T.ws[3] = c2 * s1 + s2 * c1;
    T.wc[4] = c4;
    T.ws[4] = s4;
    T.wc[5] = c4 * c1 - s4 * s1;
    T.ws[5] = c4 * s1 + s4 * c1;
    T.wc[6] = c4 * c2 - s4 * s2;
    T.ws[6] = c4 * s2 + s4 * c2;
    T.wc[7] = c4 * T.wc[3] - s4 * T.ws[3];
    T.ws[7] = c4 * T.ws[3] + s4 * T.wc[3];
    return T;
}

__device__ __forceinline__ float bmod4(float c1, float s1) {
    float c2 = 2.0f * c1 * c1 - 1.0f;
    float s2 = 2.0f * s1 * c1;
    float br = (1.0f + 4.0f * c1 + c2) * (1.0f / 6.0f);
    float bi = (4.0f * s1 + s2) * (1.0f / 6.0f);
    float d2 = br * br + bi * bi;
    return 1.0f / fmaxf(d2, 1e-7f);
}

// ---------------------------------------------------------------- manual grid barrier
// Per-block flag store + single release word. Agent-scope acquire/release.
// NBLK=512 <= HW capacity 1024 (launch_bounds(256,4) => 4 blocks/CU) => all
// blocks co-resident. Bounded spin (no hang even if assumption breaks).
__device__ __forceinline__ void grid_barrier(int* flags, int* release, int* gen) {
    __syncthreads();
    int g = *gen + 1;
    *gen = g;
    int tid = threadIdx.x, bid = blockIdx.x;
    if (bid == 0) {
        if (tid == 0) {
            __threadfence();
            __hip_atomic_store(&flags[0], g, __ATOMIC_RELEASE, __HIP_MEMORY_SCOPE_AGENT);
        }
        for (int b = tid; b < NBLK; b += NTHR) {
            int spin = 0;
            while (__hip_atomic_load(&flags[b], __ATOMIC_ACQUIRE, __HIP_MEMORY_SCOPE_AGENT) < g) {
                if (++spin > (1 << 25)) break;
                __builtin_amdgcn_s_sleep(2);
            }
        }
        __syncthreads();
        if (tid == 0) {
            __hip_atomic_store(release, g, __ATOMIC_RELEASE, __HIP_MEMORY_SCOPE_AGENT);
        }
    } else {
        if (tid == 0) {
            __threadfence();
            __hip_atomic_store(&flags[bid], g, __ATOMIC_RELEASE, __HIP_MEMORY_SCOPE_AGENT);
            int spin = 0;
            while (__hip_atomic_load(release, __ATOMIC_ACQUIRE, __HIP_MEMORY_SCOPE_AGENT) < g) {
                if (++spin > (1 << 25)) break;
                __builtin_amdgcn_s_sleep(2);
            }
        }
    }
    __syncthreads();
}

// ---------------------------------------------------------------- fused kernel
__global__ __launch_bounds__(NTHR, 4) void pme_fused(
    const float* __restrict__ pos, const float* __restrict__ chg,
    const float* __restrict__ box, const int* __restrict__ excl, int N, int E,
    int* __restrict__ flags, int* __restrict__ release, float* __restrict__ grid,
    float2* __restrict__ bufA, float2* __restrict__ bufB, float4* __restrict__ pxq,
    double* __restrict__ partB, float* __restrict__ out) {
    __shared__ union Smem {
        float g[4][KG];
        float2 c[4][KG];
        float4 sj[DJT];
        double fsum[4];
    } sm;

    int tid = threadIdx.x, bid = blockIdx.x;
    int gid = bid * NTHR + tid;
    int wv = tid >> 6, ln = tid & 63;
    int waveId = bid * 4 + wv;
    int gen = 0;
    BoxInfo B = load_box(box);

    // ---- ph0: zero grid + pack pxq
    for (int c = gid; c < KG3; c += NBLK * NTHR) grid[c] = 0.0f;
    if (gid < N) pxq[gid] = make_float4(pos[3 * gid], pos[3 * gid + 1], pos[3 * gid + 2], chg[gid]);
    grid_barrier(flags, release, &gen);

    // ---- ph1: spread, 64 work-items per atom (grid-stride)
    for (int w = gid; w < N * 64; w += NBLK * NTHR) {
        int atom = w >> 6, sub = w & 63;
        int jx = sub >> 4, jy = (sub >> 2) & 3, jz = sub & 3;
        float4 a = pxq[atom];
        float wx[4], wy[4], wz[4];
        int bx, by, bz;
        {
            float f = a.x * B.inv[0] + a.y * B.inv[3] + a.z * B.inv[6];
            f -= floorf(f);
            float u = f * (float)KG, fu = floorf(u);
            bx = (int)fu;
            bspline4(u - fu, wx);
            f = a.x * B.inv[1] + a.y * B.inv[4] + a.z * B.inv[7];
            f -= floorf(f);
            u = f * (float)KG;
            fu = floorf(u);
            by = (int)fu;
            bspline4(u - fu, wy);
            f = a.x * B.inv[2] + a.y * B.inv[5] + a.z * B.inv[8];
            f -= floorf(f);
            u = f * (float)KG;
            fu = floorf(u);
            bz = (int)fu;
            bspline4(u - fu, wz);
        }
        int gx = (bx - 3 + jx + 2 * KG) & (KG - 1);
        int gy = (by - 3 + jy + 2 * KG) & (KG - 1);
        int gz = (bz - 3 + jz + 2 * KG) & (KG - 1);
        float val = a.w * sel4(wx, jx) * sel4(wy, jy) * sel4(wz, jz);
        atomicAdd(&grid[(gx * KG + gy) * KG + gz], val);
    }
    grid_barrier(flags, release, &gen);

    // ---- ph2: dft_z — 4096 lines, 2 per wave. grid[ix][iy][iz] -> bufA[ix][mz][iy]
    for (int it = 0; it < 2; it++) {
        int line = it * NWAVE + waveId;  // ix*KG + iy
        __syncthreads();
        sm.g[wv][ln] = grid[line * KG + ln];
        __syncthreads();
        Tw8 T = make_tw8(ln);
        float rr[8] = {0}, ii[8] = {0};
#pragma unroll
        for (int s = 0; s < 8; s++) {
#pragma unroll
            for (int g8 = 0; g8 < 8; g8++) {
                float gv = sm.g[wv][s * 8 + g8];
                rr[g8] = fmaf(gv, T.wc[g8], rr[g8]);
                ii[g8] = fmaf(gv, T.ws[g8], ii[g8]);
                float nc = T.wc[g8] * T.c8 - T.ws[g8] * T.s8;
                T.ws[g8] = T.wc[g8] * T.s8 + T.ws[g8] * T.c8;
                T.wc[g8] = nc;
            }
        }
        if (ln < MZK) {
            float re = ((rr[0] + rr[1]) + (rr[2] + rr[3])) + ((rr[4] + rr[5]) + (rr[6] + rr[7]));
            float im = ((ii[0] + ii[1]) + (ii[2] + ii[3])) + ((ii[4] + ii[5]) + (ii[6] + ii[7]));
            int ix = line >> 6, iy = line & 63;
            bufA[(ix * KG + ln) * KG + iy] = make_float2(re, im);
        }
    }
    grid_barrier(flags, release, &gen);

    // ---- ph3: dft_y — 2112 lines (ix, mz<=32). bufA[ix][mz][iy] -> bufB[my][mz][ix]
    for (int it = 0; it < 2; it++) {
        int idx = it * NWAVE + waveId;
        bool act = idx < KG * MZK;
        int ix = act ? idx / MZK : 0;
        int mz = act ? idx - ix * MZK : 0;
        __syncthreads();
        if (act) sm.c[wv][ln] = bufA[(ix * KG + mz) * KG + ln];
        __syncthreads();
        if (act) {
            Tw8 T = make_tw8(ln);
            float rr[8] = {0}, ii[8] = {0};
#pragma unroll
            for (int s = 0; s < 8; s++) {
#pragma unroll
                for (int g8 = 0; g8 < 8; g8++) {
                    float2 a = sm.c[wv][s * 8 + g8];
                    rr[g8] += a.x * T.wc[g8] - a.y * T.ws[g8];
                    ii[g8] += a.x * T.ws[g8] + a.y * T.wc[g8];
                    float nc = T.wc[g8] * T.c8 - T.ws[g8] * T.s8;
                    T.ws[g8] = T.wc[g8] * T.s8 + T.ws[g8] * T.c8;
                    T.wc[g8] = nc;
                }
            }
            float re = ((rr[0] + rr[1]) + (rr[2] + rr[3])) + ((rr[4] + rr[5]) + (rr[6] + rr[7]));
            float im = ((ii[0] + ii[1]) + (ii[2] + ii[3])) + ((ii[4] + ii[5]) + (ii[6] + ii[7]));
            bufB[(ln * MZK + mz) * KG + ix] = make_float2(re, im);
        }
    }
    grid_barrier(flags, release, &gen);

    double e = 0.0;  // per-thread energy accumulator (recip + direct)

    // ---- ph4: dft_x + influence — 2112 lines (my, mz<=32), lane = mx
    for (int it = 0; it < 2; it++) {
        int idx = it * NWAVE + waveId;
        bool act = idx < KG * MZK;
        int my = act ? idx / MZK : 0;
        int mz = act ? idx - my * MZK : 0;
        __syncthreads();
        if (act) sm.c[wv][ln] = bufB[(my * MZK + mz) * KG + ln];
        __syncthreads();
        if (act) {
            Tw8 T = make_tw8(ln);
            float rr[8] = {0}, ii[8] = {0};
#pragma unroll
            for (int s = 0; s < 8; s++) {
#pragma unroll
                for (int g8 = 0; g8 < 8; g8++) {
                    float2 a = sm.c[wv][s * 8 + g8];
                    rr[g8] += a.x * T.wc[g8] - a.y * T.ws[g8];
                    ii[g8] += a.x * T.ws[g8] + a.y * T.wc[g8];
                    float nc = T.wc[g8] * T.c8 - T.ws[g8] * T.s8;
                    T.ws[g8] = T.wc[g8] * T.s8 + T.ws[g8] * T.c8;
                    T.wc[g8] = nc;
                }
            }
            float re = ((rr[0] + rr[1]) + (rr[2] + rr[3])) + ((rr[4] + rr[5]) + (rr[6] + rr[7]));
            float im = ((ii[0] + ii[1]) + (ii[2] + ii[3])) + ((ii[4] + ii[5]) + (ii[6] + ii[7]));
            float sq = re * re + im * im;

            int mx = ln;
            int msx = (mx < KG / 2) ? mx : mx - KG;
            int msy = (my < KG / 2) ? my : my - KG;
            int msz = (mz < KG / 2) ? mz : mz - KG;
            float fmx = (float)msx, fmy = (float)msy, fmz = (float)msz;
            float kx = fmx * B.inv[0] + fmy * B.inv[1] + fmz * B.inv[2];
            float ky = fmx * B.inv[3] + fmy * B.inv[4] + fmz * B.inv[5];
            float kz = fmx * B.inv[6] + fmy * B.inv[7] + fmz * B.inv[8];
            float msq = kx * kx + ky * ky + kz * kz;
            const float cexp = (PI_F * PI_F) / (ALPHA * ALPHA);
            float infl = (msq > 0.0f) ? __expf(-cexp * msq) / msq : 0.0f;
            float bx_ = bmod4(T.c1, T.s1);
            float sy, cy, sz, cz;
            __sincosf(2.0f * PI_F * (float)my / (float)KG, &sy, &cy);
            __sincosf(2.0f * PI_F * (float)mz / (float)KG, &sz, &cz);
            float by_ = bmod4(cy, sy);
            float bz_ = bmod4(cz, sz);
            float wgt = (mz == 0 || mz == 32) ? 1.0f : 2.0f;
            float pref = COULOMB / (2.0f * PI_F * B.vol);
            e += (double)(wgt * pref * infl * bx_ * by_ * bz_ * sq);
        }
    }
    // no grid barrier needed: ph5 reads only pxq (visible since ph0->ph1 barrier)

    // ---- ph5: direct space — grid-stride over (i-super 256) x (j-tile 32) combos
    {
        int nib = (N + DIB - 1) / DIB;
        int njt = (N + DJT - 1) / DJT;
        int ncombo = nib * njt;
        int iters = (ncombo + NBLK - 1) / NBLK;
        int ne = (E < 8) ? E : 8;
        for (int it = 0; it < iters; it++) {
            int c = bid + it * NBLK;
            bool have = c < ncombo;
            int ci = have ? c % nib : 0;
            int cj = have ? c / nib : 0;
            int ib = ci * DIB, jb = cj * DJT;
            __syncthreads();
            if (tid < DJT) {
                int jg0 = jb + tid;
                sm.sj[tid] = (have && jg0 < N) ? pxq[jg0] : make_float4(0.0f, 0.0f, 0.0f, 0.0f);
            }
            __syncthreads();
            int i = ib + tid;
            bool active = have && (jb + DJT > ib) && (i < N);
            if (active) {
                float4 me = pxq[i];
                float xi = me.x, yi = me.y, zi = me.z, qi = me.w;
                int ex[8];
                for (int k = 0; k < ne; k++) ex[k] = excl[i * E + k];
                float fsum = 0.0f;
                if (B.diag) {
                    float Lx = box[0], Ly = box[4], Lz = box[8];
                    float ivx = B.inv[0], ivy = B.inv[4], ivz = B.inv[8];
#pragma unroll 8
                    for (int jj = 0; jj < DJT; jj++) {
                        float4 o = sm.sj[jj];
                        int jg = jb + jj;
                        float dx = xi - o.x, dy = yi - o.y, dz = zi - o.z;
                        dx -= rintf(dx * ivx) * Lx;
                        dy -= rintf(dy * ivy) * Ly;
                        dz -= rintf(dz * ivz) * Lz;
                        float r2 = fmaf(dx, dx, fmaf(dy, dy, dz * dz));
                        bool valid = (r2 < CUTOFF2) & (jg > i) & (jg < N);
                        for (int k = 0; k < ne; k++) valid = valid & (ex[k] != jg);
                        float r2m = valid ? r2 : 1.0f;
                        float rinv = __builtin_amdgcn_rsqf(r2m);
                        float r = r2m * rinv;
                        float g = erfc_fast(ALPHA * r) * rinv;
                        float qqm = valid ? qi * o.w : 0.0f;
                        fsum = fmaf(qqm, g, fsum);
                    }
                } else {
#pragma unroll 4
                    for (int jj = 0; jj < DJT; jj++) {
                        float4 o = sm.sj[jj];
                        int jg = jb + jj;
                        float dx = xi - o.x, dy = yi - o.y, dz = zi - o.z;
                        float s0 = dx * B.inv[0] + dy * B.inv[3] + dz * B.inv[6];
                        float s1 = dx * B.inv[1] + dy * B.inv[4] + dz * B.inv[7];
                        float s2 = dx * B.inv[2] + dy * B.inv[5] + dz * B.inv[8];
                        s0 -= rintf(s0);
                        s1 -= rintf(s1);
                        s2 -= rintf(s2);
                        float ddx = s0 * box[0] + s1 * box[3] + s2 * box[6];
                        float ddy = s0 * box[1] + s1 * box[4] + s2 * box[7];
                        float ddz = s0 * box[2] + s1 * box[5] + s2 * box[8];
                        float r2 = fmaf(ddx, ddx, fmaf(ddy, ddy, ddz * ddz));
                        bool valid = (r2 < CUTOFF2) & (jg > i) & (jg < N);
                        for (int k = 0; k < ne; k++) valid = valid & (ex[k] != jg);
                        float r2m = valid ? r2 : 1.0f;
                        float rinv = __builtin_amdgcn_rsqf(r2m);
                        float r = r2m * rinv;
                        float g = erfc_fast(ALPHA * r) * rinv;
                        float qqm = valid ? qi * o.w : 0.0f;
                        fsum = fmaf(qqm, g, fsum);
                    }
                }
                e += (double)(COULOMB * fsum);
                // anchor tile: self-energy + exclusion corrections
                if (jb == ib) {
                    const float inv_sqrt_pi = 0.5641895835477563f;
                    float corr = -ALPHA * inv_sqrt_pi * qi * qi;
                    for (int k = 0; k < ne; k++) {
                        int j = ex[k];
                        if (j < 0) continue;
                        float4 o = pxq[j];
                        float dx = xi - o.x, dy = yi - o.y, dz = zi - o.z;
                        if (B.diag) {
                            dx -= rintf(dx * B.inv[0]) * box[0];
                            dy -= rintf(dy * B.inv[4]) * box[4];
                            dz -= rintf(dz * B.inv[8]) * box[8];
                        } else {
                            float s0 = dx * B.inv[0] + dy * B.inv[3] + dz * B.inv[6];
                            float s1 = dx * B.inv[1] + dy * B.inv[4] + dz * B.inv[7];
                            float s2 = dx * B.inv[2] + dy * B.inv[5] + dz * B.inv[8];
                            s0 -= rintf(s0);
                            s1 -= rintf(s1);
                            s2 -= rintf(s2);
                            dx = s0 * box[0] + s1 * box[3] + s2 * box[6];
                            dy = s0 * box[1] + s1 * box[4] + s2 * box[7];
                            dz = s0 * box[2] + s1 * box[5] + s2 * box[8];
                        }
                        float r2 = dx * dx + dy * dy + dz * dz;
                        if (r2 > 0.0f) {
                            float rinv = __builtin_amdgcn_rsqf(r2);
                            float r = r2 * rinv;
                            float erfv = 1.0f - erfc_fast(ALPHA * r);
                            corr += -0.5f * qi * o.w * erfv * rinv;
                        }
                    }
                    e += (double)(COULOMB * corr);
                }
            }
        }
    }

    // ---- ph6: block reduce -> partB[bid]
    __syncthreads();
#pragma unroll
    for (int off = 32; off > 0; off >>= 1) e += __shfl_down(e, off, 64);
    if (ln == 0) sm.fsum[wv] = e;
    __syncthreads();
    if (tid == 0) partB[bid] = sm.fsum[0] + sm.fsum[1] + sm.fsum[2] + sm.fsum[3];
    grid_barrier(flags, release, &gen);

    // ---- ph7: block 0 sums 512 partials -> out
    if (bid == 0) {
        double s = 0.0;
        for (int k = tid; k < NBLK; k += NTHR) s += partB[k];
#pragma unroll
        for (int off = 32; off > 0; off >>= 1) s += __shfl_down(s, off, 64);
        __syncthreads();
        if (ln == 0) sm.fsum[wv] = s;
        __syncthreads();
        if (tid == 0) out[0] = (float)(sm.fsum[0] + sm.fsum[1] + sm.fsum[2] + sm.fsum[3]);
    }
}

// ---------------------------------------------------------------- launch

extern "C" void kernel_launch(void* const* d_in, const int* in_sizes, int n_in,
                              void* d_out, int out_size, void* d_ws, size_t ws_size,
                              hipStream_t stream) {
    const float* pos = (const float*)d_in[0];
    const float* chg = (const float*)d_in[1];
    const float* box = (const float*)d_in[2];
    const int* excl = (const int*)d_in[3];
    int N = in_sizes[0] / 3;
    int E = in_sizes[3] / N;

    char* ws = (char*)d_ws;
    int* flags = (int*)ws;                          // 512 ints
    int* release = (int*)(ws + 2048);               // 1 int
    double* partB = (double*)(ws + 4096);           // 512 doubles (all written)
    float* grid = (float*)(ws + 0x10000);           // 1 MB (zeroed in-kernel)
    float2* bufA = (float2*)(ws + 0x110000);        // 2 MB
    float2* bufB = (float2*)(ws + 0x310000);        // ~1.1 MB
    float4* pxq = (float4*)(ws + 0x430000);         // 64 KB
    float* out = (float*)d_out;

    // zero barrier flags + release (tiny, in-graph so re-run every replay)
    hipMemsetAsync(ws, 0, 4096, stream);

    pme_fused<<<NBLK, NTHR, 0, stream>>>(pos, chg, box, excl, N, E, flags, release, grid,
                                         bufA, bufB, pxq, partB, out);
}

// Round 7
// 310.856 us; speedup vs baseline: 2.5006x; 2.5006x over previous
//
#include <hip/hip_runtime.h>
#include <math.h>
#include <stdint.h>

#define KG 64
#define KG3 (KG * KG * KG)
#define MZK 33  // Hermitian: mz in [0,32]
#define DIB 256
#define DJT 32
#define ALPHA 0.34f
#define COULOMB 138.935456f
#define CUTOFF2 81.0f
#define PI_F 3.14159265358979323846f

// ---------------------------------------------------------------- helpers
struct BoxInfo {
    float inv[9];
    float vol;
    bool diag;
};
__device__ __forceinline__ BoxInfo load_box(const float* __restrict__ box) {
    BoxInfo b;
    float b0 = box[0], b1 = box[1], b2 = box[2];
    float b3 = box[3], b4 = box[4], b5 = box[5];
    float b6 = box[6], b7 = box[7], b8 = box[8];
    float det = b0 * (b4 * b8 - b5 * b7) - b1 * (b3 * b8 - b5 * b6) + b2 * (b3 * b7 - b4 * b6);
    float id = 1.0f / det;
    b.inv[0] = (b4 * b8 - b5 * b7) * id;
    b.inv[1] = (b2 * b7 - b1 * b8) * id;
    b.inv[2] = (b1 * b5 - b2 * b4) * id;
    b.inv[3] = (b5 * b6 - b3 * b8) * id;
    b.inv[4] = (b0 * b8 - b2 * b6) * id;
    b.inv[5] = (b2 * b3 - b0 * b5) * id;
    b.inv[6] = (b3 * b7 - b4 * b6) * id;
    b.inv[7] = (b1 * b6 - b0 * b7) * id;
    b.inv[8] = (b0 * b4 - b1 * b3) * id;
    b.vol = fabsf(det);
    b.diag = (b1 == 0.0f) && (b2 == 0.0f) && (b3 == 0.0f) && (b5 == 0.0f) && (b6 == 0.0f) &&
             (b7 == 0.0f);
    return b;
}

// fast erfc, Abramowitz-Stegun 7.1.26, |abs err| < 1.5e-7 for x >= 0
__device__ __forceinline__ float erfc_fast(float x) {
    float t = __builtin_amdgcn_rcpf(fmaf(0.3275911f, x, 1.0f));
    float p = fmaf(t, 1.061405429f, -1.453152027f);
    p = fmaf(t, p, 1.421413741f);
    p = fmaf(t, p, -0.284496736f);
    p = fmaf(t, p, 0.254829592f);
    return t * p * __expf(-x * x);
}

__device__ __forceinline__ void bspline4(float t, float* w) {
    float w0 = 1.0f - t, w1 = t;
    float a2 = 0.5f * t * w1;
    float a1 = 0.5f * ((t + 1.0f) * w0 + (2.0f - t) * w1);
    float a0 = 0.5f * (1.0f - t) * w0;
    const float d = 1.0f / 3.0f;
    w[3] = d * t * a2;
    w[2] = d * ((t + 1.0f) * a1 + (3.0f - t) * a2);
    w[1] = d * ((t + 2.0f) * a0 + (2.0f - t) * a1);
    w[0] = d * (1.0f - t) * a0;
}

__device__ __forceinline__ float sel4(const float* w, int j) {
    float r = w[0];
    r = (j == 1) ? w[1] : r;
    r = (j == 2) ? w[2] : r;
    r = (j == 3) ? w[3] : r;
    return r;
}

// ILP-8 twiddle chains
struct Tw8 {
    float wc[8], ws[8], c8, s8, c1, s1;
};
__device__ __forceinline__ Tw8 make_tw8(int m) {
    Tw8 T;
    float s1, c1;
    __sincosf(-2.0f * PI_F * (float)m / (float)KG, &s1, &c1);
    T.c1 = c1;
    T.s1 = s1;
    float c2 = c1 * c1 - s1 * s1, s2 = 2.0f * c1 * s1;
    float c4 = c2 * c2 - s2 * s2, s4 = 2.0f * c2 * s2;
    T.c8 = c4 * c4 - s4 * s4;
    T.s8 = 2.0f * c4 * s4;
    T.wc[0] = 1.0f;
    T.ws[0] = 0.0f;
    T.wc[1] = c1;
    T.ws[1] = s1;
    T.wc[2] = c2;
    T.ws[2] = s2;
    T.wc[3] = c2 * c1 - s2 * s1;
    T.ws[3] = c2 * s1 + s2 * c1;
    T.wc[4] = c4;
    T.ws[4] = s4;
    T.wc[5] = c4 * c1 - s4 * s1;
    T.ws[5] = c4 * s1 + s4 * c1;
    T.wc[6] = c4 * c2 - s4 * s2;
    T.ws[6] = c4 * s2 + s4 * c2;
    T.wc[7] = c4 * T.wc[3] - s4 * T.ws[3];
    T.ws[7] = c4 * T.ws[3] + s4 * T.wc[3];
    return T;
}

__device__ __forceinline__ float bmod4(float c1, float s1) {
    float c2 = 2.0f * c1 * c1 - 1.0f;
    float s2 = 2.0f * s1 * c1;
    float br = (1.0f + 4.0f * c1 + c2) * (1.0f / 6.0f);
    float bi = (4.0f * s1 + s2) * (1.0f / 6.0f);
    float d2 = br * br + bi * bi;
    return 1.0f / fmaxf(d2, 1e-7f);
}

// ---------------------------------------------------------------- spreading
// 16 threads per atom (jx,jy combos), 4 z-atomics each.
__global__ __launch_bounds__(256) void spread_kernel(const float* __restrict__ pos,
                                                     const float* __restrict__ chg,
                                                     const float* __restrict__ box,
                                                     float* __restrict__ grid,
                                                     float4* __restrict__ pxq, int N) {
    int t16 = blockIdx.x * blockDim.x + threadIdx.x;
    int i = t16 >> 4, sub = t16 & 15;
    if (i >= N) return;
    int jx = sub >> 2, jy = sub & 3;
    BoxInfo B = load_box(box);
    float p0 = pos[3 * i], p1 = pos[3 * i + 1], p2 = pos[3 * i + 2];
    float q = chg[i];
    if (sub == 0) pxq[i] = make_float4(p0, p1, p2, q);
    float w[3][4];
    int idx[3][4];
#pragma unroll
    for (int a = 0; a < 3; a++) {
        float f = p0 * B.inv[0 * 3 + a] + p1 * B.inv[1 * 3 + a] + p2 * B.inv[2 * 3 + a];
        f -= floorf(f);
        float u = f * (float)KG;
        float fu = floorf(u);
        int base = (int)fu;
        float tt = u - fu;
        bspline4(tt, w[a]);
#pragma unroll
        for (int j = 0; j < 4; j++) idx[a][j] = (base - 3 + j + 2 * KG) & (KG - 1);
    }
    float qxy = q * sel4(w[0], jx) * sel4(w[1], jy);
    int bxy = (idx[0][jx] * KG + idx[1][jy]) * KG;
#pragma unroll
    for (int jz = 0; jz < 4; jz++) {
        atomicAdd(&grid[bxy + idx[2][jz]], qxy * w[2][jz]);
    }
}

// ---------------------------------------------------------------- dft2d: z then y per ix-plane
// One block per ix (64 blocks x 1024 threads). grid[ix][iy][iz] -> bufA[(my*MZK+mz)*KG+ix]
__global__ __launch_bounds__(1024) void dft2d_yz(const float* __restrict__ grid,
                                                 float2* __restrict__ bufA) {
    __shared__ float Pl[KG * KG];          // 16 KB real plane
    __shared__ float2 Qs[KG][MZK + 1];     // z-DFT result, padded row (17 KB)
    int ix = blockIdx.x;
    int tid = threadIdx.x;
    int wv = tid >> 6, ln = tid & 63;

    const float* gp = grid + ix * KG * KG;
    for (int k = tid; k < KG * KG; k += 1024) Pl[k] = gp[k];
    __syncthreads();

    // phase A: z-DFT along iz for each iy line; lane = mz (keep mz < MZK)
    for (int r = 0; r < 4; r++) {
        int iy = wv + r * 16;
        Tw8 T = make_tw8(ln);
        float rr[8] = {0}, ii[8] = {0};
#pragma unroll
        for (int s = 0; s < 8; s++) {
#pragma unroll
            for (int g8 = 0; g8 < 8; g8++) {
                float gv = Pl[iy * KG + s * 8 + g8];
                rr[g8] = fmaf(gv, T.wc[g8], rr[g8]);
                ii[g8] = fmaf(gv, T.ws[g8], ii[g8]);
                float nc = T.wc[g8] * T.c8 - T.ws[g8] * T.s8;
                T.ws[g8] = T.wc[g8] * T.s8 + T.ws[g8] * T.c8;
                T.wc[g8] = nc;
            }
        }
        if (ln < MZK) {
            float re = ((rr[0] + rr[1]) + (rr[2] + rr[3])) + ((rr[4] + rr[5]) + (rr[6] + rr[7]));
            float im = ((ii[0] + ii[1]) + (ii[2] + ii[3])) + ((ii[4] + ii[5]) + (ii[6] + ii[7]));
            Qs[iy][ln] = make_float2(re, im);
        }
    }
    __syncthreads();

    // phase B: y-DFT along iy for each mz; lane = my
    for (int mz = wv; mz < MZK; mz += 16) {
        Tw8 T = make_tw8(ln);
        float rr[8] = {0}, ii[8] = {0};
#pragma unroll
        for (int s = 0; s < 8; s++) {
#pragma unroll
            for (int g8 = 0; g8 < 8; g8++) {
                float2 a = Qs[s * 8 + g8][mz];
                rr[g8] += a.x * T.wc[g8] - a.y * T.ws[g8];
                ii[g8] += a.x * T.ws[g8] + a.y * T.wc[g8];
                float nc = T.wc[g8] * T.c8 - T.ws[g8] * T.s8;
                T.ws[g8] = T.wc[g8] * T.s8 + T.ws[g8] * T.c8;
                T.wc[g8] = nc;
            }
        }
        float re = ((rr[0] + rr[1]) + (rr[2] + rr[3])) + ((rr[4] + rr[5]) + (rr[6] + rr[7]));
        float im = ((ii[0] + ii[1]) + (ii[2] + ii[3])) + ((ii[4] + ii[5]) + (ii[6] + ii[7]));
        bufA[(ln * MZK + mz) * KG + ix] = make_float2(re, im);
    }
}

// ---------------------------------------------------------------- dft_x + influence
// 2112 lines (my, mz<=32), 4 per block (one per wave), lane = mx.
// Block partial -> atomicAdd acc[slot]; counter++ (ordered by consuming returned old).
__global__ __launch_bounds__(256) void dft_x_reduce(const float2* __restrict__ bufA,
                                                    const float* __restrict__ box,
                                                    double* __restrict__ acc,
                                                    unsigned* __restrict__ cnt) {
    __shared__ float2 c[4][KG];
    __shared__ double wsum[4];
    int tid = threadIdx.x, wv = tid >> 6, ln = tid & 63;
    int idx = blockIdx.x * 4 + wv;  // my*MZK + mz index space
    int my = idx / MZK, mz = idx - my * MZK;
    c[wv][ln] = bufA[(my * MZK + mz) * KG + ln];
    __syncthreads();
    Tw8 T = make_tw8(ln);
    float rr[8] = {0}, ii[8] = {0};
#pragma unroll
    for (int s = 0; s < 8; s++) {
#pragma unroll
        for (int g8 = 0; g8 < 8; g8++) {
            float2 a = c[wv][s * 8 + g8];
            rr[g8] += a.x * T.wc[g8] - a.y * T.ws[g8];
            ii[g8] += a.x * T.ws[g8] + a.y * T.wc[g8];
            float nc = T.wc[g8] * T.c8 - T.ws[g8] * T.s8;
            T.ws[g8] = T.wc[g8] * T.s8 + T.ws[g8] * T.c8;
            T.wc[g8] = nc;
        }
    }
    float re = ((rr[0] + rr[1]) + (rr[2] + rr[3])) + ((rr[4] + rr[5]) + (rr[6] + rr[7]));
    float im = ((ii[0] + ii[1]) + (ii[2] + ii[3])) + ((ii[4] + ii[5]) + (ii[6] + ii[7]));
    float sq = re * re + im * im;

    BoxInfo B = load_box(box);
    int mx = ln;
    int msx = (mx < KG / 2) ? mx : mx - KG;
    int msy = (my < KG / 2) ? my : my - KG;
    int msz = (mz < KG / 2) ? mz : mz - KG;
    float fmx = (float)msx, fmy = (float)msy, fmz = (float)msz;
    float kx = fmx * B.inv[0] + fmy * B.inv[1] + fmz * B.inv[2];
    float ky = fmx * B.inv[3] + fmy * B.inv[4] + fmz * B.inv[5];
    float kz = fmx * B.inv[6] + fmy * B.inv[7] + fmz * B.inv[8];
    float msq = kx * kx + ky * ky + kz * kz;
    const float cexp = (PI_F * PI_F) / (ALPHA * ALPHA);
    float infl = (msq > 0.0f) ? __expf(-cexp * msq) / msq : 0.0f;
    float bx_ = bmod4(T.c1, T.s1);
    float sy, cy, sz, cz;
    __sincosf(2.0f * PI_F * (float)my / (float)KG, &sy, &cy);
    __sincosf(2.0f * PI_F * (float)mz / (float)KG, &sz, &cz);
    float by_ = bmod4(cy, sy);
    float bz_ = bmod4(cz, sz);
    float wgt = (mz == 0 || mz == 32) ? 1.0f : 2.0f;
    float pref = COULOMB / (2.0f * PI_F * B.vol);
    double term = (double)(wgt * pref * infl * bx_ * by_ * bz_ * sq);

#pragma unroll
    for (int off = 32; off > 0; off >>= 1) term += __shfl_down(term, off, 64);
    if (ln == 0) wsum[wv] = term;
    __syncthreads();
    if (tid == 0) {
        double eb = wsum[0] + wsum[1] + wsum[2] + wsum[3];
        double old = atomicAdd(&acc[blockIdx.x & 15], eb);
        __asm__ volatile("" ::"v"(old) : "memory");  // waitcnt: acc-add acked before cnt
        atomicAdd(cnt, 1u);
    }
}

// ---------------------------------------------------------------- direct + finalize
__global__ __launch_bounds__(256) void direct_kernel(const float4* __restrict__ pxq,
                                                     const float* __restrict__ box,
                                                     const int* __restrict__ excl, int N, int E,
                                                     double* __restrict__ acc,
                                                     unsigned* __restrict__ cnt, unsigned total,
                                                     float* __restrict__ out) {
    int ib = blockIdx.x * DIB, jb = blockIdx.y * DJT;
    bool live = (jb + DJT > ib);

    __shared__ float4 sj[DJT];
    __shared__ double wsum[4];
    int tid = threadIdx.x, wv = tid >> 6, ln = tid & 63;
    if (live && tid < DJT) {
        int jg0 = jb + tid;
        sj[tid] = (jg0 < N) ? pxq[jg0] : make_float4(0.0f, 0.0f, 0.0f, 0.0f);
    }
    __syncthreads();

    BoxInfo B = load_box(box);
    double e = 0.0;
    int i = ib + tid;
    if (live && i < N) {
        float4 me = pxq[i];
        float xi = me.x, yi = me.y, zi = me.z, qi = me.w;
        int ne = (E < 8) ? E : 8;
        int ex[8];
        for (int k = 0; k < ne; k++) ex[k] = excl[i * E + k];
        float fsum = 0.0f;
        if (B.diag) {
            float Lx = box[0], Ly = box[4], Lz = box[8];
            float ivx = B.inv[0], ivy = B.inv[4], ivz = B.inv[8];
#pragma unroll 8
            for (int jj = 0; jj < DJT; jj++) {
                float4 o = sj[jj];
                int jg = jb + jj;
                float dx = xi - o.x, dy = yi - o.y, dz = zi - o.z;
                dx -= rintf(dx * ivx) * Lx;
                dy -= rintf(dy * ivy) * Ly;
                dz -= rintf(dz * ivz) * Lz;
                float r2 = fmaf(dx, dx, fmaf(dy, dy, dz * dz));
                bool valid = (r2 < CUTOFF2) & (jg > i) & (jg < N);
                for (int k = 0; k < ne; k++) valid = valid & (ex[k] != jg);
                float r2m = valid ? r2 : 1.0f;
                float rinv = __builtin_amdgcn_rsqf(r2m);
                float r = r2m * rinv;
                float g = erfc_fast(ALPHA * r) * rinv;
                float qqm = valid ? qi * o.w : 0.0f;
                fsum = fmaf(qqm, g, fsum);
            }
        } else {
#pragma unroll 4
            for (int jj = 0; jj < DJT; jj++) {
                float4 o = sj[jj];
                int jg = jb + jj;
                float dx = xi - o.x, dy = yi - o.y, dz = zi - o.z;
                float s0 = dx * B.inv[0] + dy * B.inv[3] + dz * B.inv[6];
                float s1 = dx * B.inv[1] + dy * B.inv[4] + dz * B.inv[7];
                float s2 = dx * B.inv[2] + dy * B.inv[5] + dz * B.inv[8];
                s0 -= rintf(s0);
                s1 -= rintf(s1);
                s2 -= rintf(s2);
                float ddx = s0 * box[0] + s1 * box[3] + s2 * box[6];
                float ddy = s0 * box[1] + s1 * box[4] + s2 * box[7];
                float ddz = s0 * box[2] + s1 * box[5] + s2 * box[8];
                float r2 = fmaf(ddx, ddx, fmaf(ddy, ddy, ddz * ddz));
                bool valid = (r2 < CUTOFF2) & (jg > i) & (jg < N);
                for (int k = 0; k < ne; k++) valid = valid & (ex[k] != jg);
                float r2m = valid ? r2 : 1.0f;
                float rinv = __builtin_amdgcn_rsqf(r2m);
                float r = r2m * rinv;
                float g = erfc_fast(ALPHA * r) * rinv;
                float qqm = valid ? qi * o.w : 0.0f;
                fsum = fmaf(qqm, g, fsum);
            }
        }
        e = (double)(COULOMB * fsum);

        // anchor tile: self-energy + exclusion corrections for atom i
        if (jb == ib) {
            const float inv_sqrt_pi = 0.5641895835477563f;
            float corr = -ALPHA * inv_sqrt_pi * qi * qi;
            for (int k = 0; k < ne; k++) {
                int j = ex[k];
                if (j < 0) continue;
                float4 o = pxq[j];
                float dx = xi - o.x, dy = yi - o.y, dz = zi - o.z;
                if (B.diag) {
                    dx -= rintf(dx * B.inv[0]) * box[0];
                    dy -= rintf(dy * B.inv[4]) * box[4];
                    dz -= rintf(dz * B.inv[8]) * box[8];
                } else {
                    float s0 = dx * B.inv[0] + dy * B.inv[3] + dz * B.inv[6];
                    float s1 = dx * B.inv[1] + dy * B.inv[4] + dz * B.inv[7];
                    float s2 = dx * B.inv[2] + dy * B.inv[5] + dz * B.inv[8];
                    s0 -= rintf(s0);
                    s1 -= rintf(s1);
                    s2 -= rintf(s2);
                    dx = s0 * box[0] + s1 * box[3] + s2 * box[6];
                    dy = s0 * box[1] + s1 * box[4] + s2 * box[7];
                    dz = s0 * box[2] + s1 * box[5] + s2 * box[8];
                }
                float r2 = dx * dx + dy * dy + dz * dz;
                if (r2 > 0.0f) {
                    float rinv = __builtin_amdgcn_rsqf(r2);
                    float r = r2 * rinv;
                    float erfv = 1.0f - erfc_fast(ALPHA * r);
                    corr += -0.5f * qi * o.w * erfv * rinv;
                }
            }
            e += (double)(COULOMB * corr);
        }
    }

    // block reduce -> acc slot; last block grid-wide sums the slots -> out
    __syncthreads();
#pragma unroll
    for (int off = 32; off > 0; off >>= 1) e += __shfl_down(e, off, 64);
    if (ln == 0) wsum[wv] = e;
    __syncthreads();
    if (tid == 0) {
        double eb = wsum[0] + wsum[1] + wsum[2] + wsum[3];
        int bid = blockIdx.y * gridDim.x + blockIdx.x;
        if (eb != 0.0) {
            double old = atomicAdd(&acc[bid & 15], eb);
            __asm__ volatile("" ::"v"(old) : "memory");  // acc-add acked before cnt
        }
        unsigned prev = atomicAdd(cnt, 1u);
        if (prev == total - 1u) {
            double s = 0.0;
#pragma unroll
            for (int k = 0; k < 16; k++)
                s += __hip_atomic_load(&acc[k], __ATOMIC_RELAXED, __HIP_MEMORY_SCOPE_AGENT);
            out[0] = (float)s;
        }
    }
}

// ---------------------------------------------------------------- launch

extern "C" void kernel_launch(void* const* d_in, const int* in_sizes, int n_in,
                              void* d_out, int out_size, void* d_ws, size_t ws_size,
                              hipStream_t stream) {
    const float* pos = (const float*)d_in[0];
    const float* chg = (const float*)d_in[1];
    const float* box = (const float*)d_in[2];
    const int* excl = (const int*)d_in[3];
    int N = in_sizes[0] / 3;
    int E = in_sizes[3] / N;

    char* ws = (char*)d_ws;
    double* acc = (double*)ws;                    // 16 doubles (zeroed)
    unsigned* cnt = (unsigned*)(ws + 128);        // 1 uint (zeroed)
    float* grid = (float*)(ws + 4096);            // 1 MB (zeroed)
    float2* bufA = (float2*)(ws + 0x110000);      // 2112*64 float2 ~ 1.06 MB
    float4* pxq = (float4*)(ws + 0x220000);       // 64 KB
    float* out = (float*)d_out;

    // one memset: acc + cnt + grid
    hipMemsetAsync(ws, 0, 4096 + 4 * (size_t)KG3, stream);

    spread_kernel<<<(16 * N + 255) / 256, 256, 0, stream>>>(pos, chg, box, grid, pxq, N);
    dft2d_yz<<<KG, 1024, 0, stream>>>(grid, bufA);
    dft_x_reduce<<<KG * MZK / 4, 256, 0, stream>>>(bufA, box, acc, cnt);

    int nib = (N + DIB - 1) / DIB;  // 16
    int njt = (N + DJT - 1) / DJT;  // 128
    unsigned total = (unsigned)(KG * MZK / 4 + nib * njt);  // 528 + 2048
    dim3 dg(nib, njt);
    direct_kernel<<<dg, 256, 0, stream>>>(pxq, box, excl, N, E, acc, cnt, total, out);
}

// Round 8
// 175.558 us; speedup vs baseline: 4.4278x; 1.7707x over previous
//
#include <hip/hip_runtime.h>
#include <math.h>
#include <stdint.h>

#define KG 64
#define KG3 (KG * KG * KG)
#define MZK 33  // Hermitian: mz in [0,32]
#define DIB 256
#define DJT 32
#define ALPHA 0.34f
#define COULOMB 138.935456f
#define CUTOFF2 81.0f
#define PI_F 3.14159265358979323846f

// ---------------------------------------------------------------- helpers
struct BoxInfo {
    float inv[9];
    float vol;
    bool diag;
};
__device__ __forceinline__ BoxInfo load_box(const float* __restrict__ box) {
    BoxInfo b;
    float b0 = box[0], b1 = box[1], b2 = box[2];
    float b3 = box[3], b4 = box[4], b5 = box[5];
    float b6 = box[6], b7 = box[7], b8 = box[8];
    float det = b0 * (b4 * b8 - b5 * b7) - b1 * (b3 * b8 - b5 * b6) + b2 * (b3 * b7 - b4 * b6);
    float id = 1.0f / det;
    b.inv[0] = (b4 * b8 - b5 * b7) * id;
    b.inv[1] = (b2 * b7 - b1 * b8) * id;
    b.inv[2] = (b1 * b5 - b2 * b4) * id;
    b.inv[3] = (b5 * b6 - b3 * b8) * id;
    b.inv[4] = (b0 * b8 - b2 * b6) * id;
    b.inv[5] = (b2 * b3 - b0 * b5) * id;
    b.inv[6] = (b3 * b7 - b4 * b6) * id;
    b.inv[7] = (b1 * b6 - b0 * b7) * id;
    b.inv[8] = (b0 * b4 - b1 * b3) * id;
    b.vol = fabsf(det);
    b.diag = (b1 == 0.0f) && (b2 == 0.0f) && (b3 == 0.0f) && (b5 == 0.0f) && (b6 == 0.0f) &&
             (b7 == 0.0f);
    return b;
}

// fast erfc, Abramowitz-Stegun 7.1.26, |abs err| < 1.5e-7 for x >= 0
__device__ __forceinline__ float erfc_fast(float x) {
    float t = __builtin_amdgcn_rcpf(fmaf(0.3275911f, x, 1.0f));
    float p = fmaf(t, 1.061405429f, -1.453152027f);
    p = fmaf(t, p, 1.421413741f);
    p = fmaf(t, p, -0.284496736f);
    p = fmaf(t, p, 0.254829592f);
    return t * p * __expf(-x * x);
}

__device__ __forceinline__ void bspline4(float t, float* w) {
    float w0 = 1.0f - t, w1 = t;
    float a2 = 0.5f * t * w1;
    float a1 = 0.5f * ((t + 1.0f) * w0 + (2.0f - t) * w1);
    float a0 = 0.5f * (1.0f - t) * w0;
    const float d = 1.0f / 3.0f;
    w[3] = d * t * a2;
    w[2] = d * ((t + 1.0f) * a1 + (3.0f - t) * a2);
    w[1] = d * ((t + 2.0f) * a0 + (2.0f - t) * a1);
    w[0] = d * (1.0f - t) * a0;
}

__device__ __forceinline__ float sel4(const float* w, int j) {
    float r = w[0];
    r = (j == 1) ? w[1] : r;
    r = (j == 2) ? w[2] : r;
    r = (j == 3) ? w[3] : r;
    return r;
}

// ILP-8 twiddle chains
struct Tw8 {
    float wc[8], ws[8], c8, s8, c1, s1;
};
__device__ __forceinline__ Tw8 make_tw8(int m) {
    Tw8 T;
    float s1, c1;
    __sincosf(-2.0f * PI_F * (float)m / (float)KG, &s1, &c1);
    T.c1 = c1;
    T.s1 = s1;
    float c2 = c1 * c1 - s1 * s1, s2 = 2.0f * c1 * s1;
    float c4 = c2 * c2 - s2 * s2, s4 = 2.0f * c2 * s2;
    T.c8 = c4 * c4 - s4 * s4;
    T.s8 = 2.0f * c4 * s4;
    T.wc[0] = 1.0f;
    T.ws[0] = 0.0f;
    T.wc[1] = c1;
    T.ws[1] = s1;
    T.wc[2] = c2;
    T.ws[2] = s2;
    T.wc[3] = c2 * c1 - s2 * s1;
    T.ws[3] = c2 * s1 + s2 * c1;
    T.wc[4] = c4;
    T.ws[4] = s4;
    T.wc[5] = c4 * c1 - s4 * s1;
    T.ws[5] = c4 * s1 + s4 * c1;
    T.wc[6] = c4 * c2 - s4 * s2;
    T.ws[6] = c4 * s2 + s4 * c2;
    T.wc[7] = c4 * T.wc[3] - s4 * T.ws[3];
    T.ws[7] = c4 * T.ws[3] + s4 * T.wc[3];
    return T;
}

__device__ __forceinline__ float bmod4(float c1, float s1) {
    float c2 = 2.0f * c1 * c1 - 1.0f;
    float s2 = 2.0f * s1 * c1;
    float br = (1.0f + 4.0f * c1 + c2) * (1.0f / 6.0f);
    float bi = (4.0f * s1 + s2) * (1.0f / 6.0f);
    float d2 = br * br + bi * bi;
    return 1.0f / fmaxf(d2, 1e-7f);
}

// ---------------------------------------------------------------- spreading
// 16 threads per atom (jx,jy combos), 4 z-atomics each.
__global__ __launch_bounds__(256) void spread_kernel(const float* __restrict__ pos,
                                                     const float* __restrict__ chg,
                                                     const float* __restrict__ box,
                                                     float* __restrict__ grid,
                                                     float4* __restrict__ pxq, int N) {
    int t16 = blockIdx.x * blockDim.x + threadIdx.x;
    int i = t16 >> 4, sub = t16 & 15;
    if (i >= N) return;
    int jx = sub >> 2, jy = sub & 3;
    BoxInfo B = load_box(box);
    float p0 = pos[3 * i], p1 = pos[3 * i + 1], p2 = pos[3 * i + 2];
    float q = chg[i];
    if (sub == 0) pxq[i] = make_float4(p0, p1, p2, q);
    float w[3][4];
    int idx[3][4];
#pragma unroll
    for (int a = 0; a < 3; a++) {
        float f = p0 * B.inv[0 * 3 + a] + p1 * B.inv[1 * 3 + a] + p2 * B.inv[2 * 3 + a];
        f -= floorf(f);
        float u = f * (float)KG;
        float fu = floorf(u);
        int base = (int)fu;
        float tt = u - fu;
        bspline4(tt, w[a]);
#pragma unroll
        for (int j = 0; j < 4; j++) idx[a][j] = (base - 3 + j + 2 * KG) & (KG - 1);
    }
    float qxy = q * sel4(w[0], jx) * sel4(w[1], jy);
    int bxy = (idx[0][jx] * KG + idx[1][jy]) * KG;
#pragma unroll
    for (int jz = 0; jz < 4; jz++) {
        atomicAdd(&grid[bxy + idx[2][jz]], qxy * w[2][jz]);
    }
}

// ---------------------------------------------------------------- dft2d: z then y per ix-plane
// One block per ix: 64 blocks x 512 threads (8 waves). launch_bounds(512) =>
// 256-VGPR cap — the ILP-8 state (~76 VGPR) fits, NO scratch spill (round-7's
// 1024-thread version spilled at the 64-VGPR cap: 208 MB HBM traffic, 192 us).
__global__ __launch_bounds__(512) void dft2d_yz(const float* __restrict__ grid,
                                                float2* __restrict__ bufA) {
    __shared__ float Pl[KG * KG];       // 16 KB real plane
    __shared__ float2 Qs[KG][MZK + 1];  // z-DFT result, padded row (17 KB)
    int ix = blockIdx.x;
    int tid = threadIdx.x;
    int wv = tid >> 6, ln = tid & 63;  // 8 waves

    const float* gp = grid + ix * KG * KG;
    for (int k = tid; k < KG * KG; k += 512) Pl[k] = gp[k];
    __syncthreads();

    // phase A: z-DFT along iz for each iy line; lane = mz (keep mz < MZK)
    for (int r = 0; r < 8; r++) {
        int iy = wv + r * 8;
        Tw8 T = make_tw8(ln);
        float rr[8] = {0}, ii[8] = {0};
#pragma unroll
        for (int s = 0; s < 8; s++) {
#pragma unroll
            for (int g8 = 0; g8 < 8; g8++) {
                float gv = Pl[iy * KG + s * 8 + g8];
                rr[g8] = fmaf(gv, T.wc[g8], rr[g8]);
                ii[g8] = fmaf(gv, T.ws[g8], ii[g8]);
                float nc = T.wc[g8] * T.c8 - T.ws[g8] * T.s8;
                T.ws[g8] = T.wc[g8] * T.s8 + T.ws[g8] * T.c8;
                T.wc[g8] = nc;
            }
        }
        if (ln < MZK) {
            float re = ((rr[0] + rr[1]) + (rr[2] + rr[3])) + ((rr[4] + rr[5]) + (rr[6] + rr[7]));
            float im = ((ii[0] + ii[1]) + (ii[2] + ii[3])) + ((ii[4] + ii[5]) + (ii[6] + ii[7]));
            Qs[iy][ln] = make_float2(re, im);
        }
    }
    __syncthreads();

    // phase B: y-DFT along iy for each mz; lane = my
    for (int mz = wv; mz < MZK; mz += 8) {
        Tw8 T = make_tw8(ln);
        float rr[8] = {0}, ii[8] = {0};
#pragma unroll
        for (int s = 0; s < 8; s++) {
#pragma unroll
            for (int g8 = 0; g8 < 8; g8++) {
                float2 a = Qs[s * 8 + g8][mz];
                rr[g8] += a.x * T.wc[g8] - a.y * T.ws[g8];
                ii[g8] += a.x * T.ws[g8] + a.y * T.wc[g8];
                float nc = T.wc[g8] * T.c8 - T.ws[g8] * T.s8;
                T.ws[g8] = T.wc[g8] * T.s8 + T.ws[g8] * T.c8;
                T.wc[g8] = nc;
            }
        }
        float re = ((rr[0] + rr[1]) + (rr[2] + rr[3])) + ((rr[4] + rr[5]) + (rr[6] + rr[7]));
        float im = ((ii[0] + ii[1]) + (ii[2] + ii[3])) + ((ii[4] + ii[5]) + (ii[6] + ii[7]));
        bufA[(ln * MZK + mz) * KG + ix] = make_float2(re, im);
    }
}

// ---------------------------------------------------------------- dft_x + influence
// 2112 lines (my, mz<=32), 4 per block (one per wave), lane = mx.
// Block partial -> atomicAdd acc[slot]; counter++ (ordered by consuming returned old).
__global__ __launch_bounds__(256) void dft_x_reduce(const float2* __restrict__ bufA,
                                                    const float* __restrict__ box,
                                                    double* __restrict__ acc,
                                                    unsigned* __restrict__ cnt) {
    __shared__ float2 c[4][KG];
    __shared__ double wsum[4];
    int tid = threadIdx.x, wv = tid >> 6, ln = tid & 63;
    int idx = blockIdx.x * 4 + wv;  // my*MZK + mz index space
    int my = idx / MZK, mz = idx - my * MZK;
    c[wv][ln] = bufA[(my * MZK + mz) * KG + ln];
    __syncthreads();
    Tw8 T = make_tw8(ln);
    float rr[8] = {0}, ii[8] = {0};
#pragma unroll
    for (int s = 0; s < 8; s++) {
#pragma unroll
        for (int g8 = 0; g8 < 8; g8++) {
            float2 a = c[wv][s * 8 + g8];
            rr[g8] += a.x * T.wc[g8] - a.y * T.ws[g8];
            ii[g8] += a.x * T.ws[g8] + a.y * T.wc[g8];
            float nc = T.wc[g8] * T.c8 - T.ws[g8] * T.s8;
            T.ws[g8] = T.wc[g8] * T.s8 + T.ws[g8] * T.c8;
            T.wc[g8] = nc;
        }
    }
    float re = ((rr[0] + rr[1]) + (rr[2] + rr[3])) + ((rr[4] + rr[5]) + (rr[6] + rr[7]));
    float im = ((ii[0] + ii[1]) + (ii[2] + ii[3])) + ((ii[4] + ii[5]) + (ii[6] + ii[7]));
    float sq = re * re + im * im;

    BoxInfo B = load_box(box);
    int mx = ln;
    int msx = (mx < KG / 2) ? mx : mx - KG;
    int msy = (my < KG / 2) ? my : my - KG;
    int msz = (mz < KG / 2) ? mz : mz - KG;
    float fmx = (float)msx, fmy = (float)msy, fmz = (float)msz;
    float kx = fmx * B.inv[0] + fmy * B.inv[1] + fmz * B.inv[2];
    float ky = fmx * B.inv[3] + fmy * B.inv[4] + fmz * B.inv[5];
    float kz = fmx * B.inv[6] + fmy * B.inv[7] + fmz * B.inv[8];
    float msq = kx * kx + ky * ky + kz * kz;
    const float cexp = (PI_F * PI_F) / (ALPHA * ALPHA);
    float infl = (msq > 0.0f) ? __expf(-cexp * msq) / msq : 0.0f;
    float bx_ = bmod4(T.c1, T.s1);
    float sy, cy, sz, cz;
    __sincosf(2.0f * PI_F * (float)my / (float)KG, &sy, &cy);
    __sincosf(2.0f * PI_F * (float)mz / (float)KG, &sz, &cz);
    float by_ = bmod4(cy, sy);
    float bz_ = bmod4(cz, sz);
    float wgt = (mz == 0 || mz == 32) ? 1.0f : 2.0f;
    float pref = COULOMB / (2.0f * PI_F * B.vol);
    double term = (double)(wgt * pref * infl * bx_ * by_ * bz_ * sq);

#pragma unroll
    for (int off = 32; off > 0; off >>= 1) term += __shfl_down(term, off, 64);
    if (ln == 0) wsum[wv] = term;
    __syncthreads();
    if (tid == 0) {
        double eb = wsum[0] + wsum[1] + wsum[2] + wsum[3];
        double old = atomicAdd(&acc[blockIdx.x & 15], eb);
        __asm__ volatile("" ::"v"(old) : "memory");  // acc-add acked before cnt
        atomicAdd(cnt, 1u);
    }
}

// ---------------------------------------------------------------- direct + finalize
// 1D launch over only the 1088 live (ci,cj) combos (upper-triangular tiles).
__global__ __launch_bounds__(256) void direct_kernel(const float4* __restrict__ pxq,
                                                     const float* __restrict__ box,
                                                     const int* __restrict__ excl, int N, int E,
                                                     int nib, int njt,
                                                     double* __restrict__ acc,
                                                     unsigned* __restrict__ cnt, unsigned total,
                                                     float* __restrict__ out) {
    // decode linear block id -> (ci, cj): live cj range for ci is [ratio*ci, njt)
    int lin = blockIdx.x;
    int ratio = DIB / DJT;  // 8
    int ci = 0;
    for (; ci < nib; ci++) {
        int cnt_ci = njt - ratio * ci;
        if (lin < cnt_ci) break;
        lin -= cnt_ci;
    }
    int cj = ratio * ci + lin;
    int ib = ci * DIB, jb = cj * DJT;

    __shared__ float4 sj[DJT];
    __shared__ double wsum[4];
    int tid = threadIdx.x, wv = tid >> 6, ln = tid & 63;
    if (tid < DJT) {
        int jg0 = jb + tid;
        sj[tid] = (jg0 < N) ? pxq[jg0] : make_float4(0.0f, 0.0f, 0.0f, 0.0f);
    }
    __syncthreads();

    BoxInfo B = load_box(box);
    double e = 0.0;
    int i = ib + tid;
    if (i < N) {
        float4 me = pxq[i];
        float xi = me.x, yi = me.y, zi = me.z, qi = me.w;
        int ne = (E < 8) ? E : 8;
        int ex[8];
        for (int k = 0; k < ne; k++) ex[k] = excl[i * E + k];
        float fsum = 0.0f;
        if (B.diag) {
            float Lx = box[0], Ly = box[4], Lz = box[8];
            float ivx = B.inv[0], ivy = B.inv[4], ivz = B.inv[8];
#pragma unroll 8
            for (int jj = 0; jj < DJT; jj++) {
                float4 o = sj[jj];
                int jg = jb + jj;
                float dx = xi - o.x, dy = yi - o.y, dz = zi - o.z;
                dx -= rintf(dx * ivx) * Lx;
                dy -= rintf(dy * ivy) * Ly;
                dz -= rintf(dz * ivz) * Lz;
                float r2 = fmaf(dx, dx, fmaf(dy, dy, dz * dz));
                bool valid = (r2 < CUTOFF2) & (jg > i) & (jg < N);
                for (int k = 0; k < ne; k++) valid = valid & (ex[k] != jg);
                float r2m = valid ? r2 : 1.0f;
                float rinv = __builtin_amdgcn_rsqf(r2m);
                float r = r2m * rinv;
                float g = erfc_fast(ALPHA * r) * rinv;
                float qqm = valid ? qi * o.w : 0.0f;
                fsum = fmaf(qqm, g, fsum);
            }
        } else {
#pragma unroll 4
            for (int jj = 0; jj < DJT; jj++) {
                float4 o = sj[jj];
                int jg = jb + jj;
                float dx = xi - o.x, dy = yi - o.y, dz = zi - o.z;
                float s0 = dx * B.inv[0] + dy * B.inv[3] + dz * B.inv[6];
                float s1 = dx * B.inv[1] + dy * B.inv[4] + dz * B.inv[7];
                float s2 = dx * B.inv[2] + dy * B.inv[5] + dz * B.inv[8];
                s0 -= rintf(s0);
                s1 -= rintf(s1);
                s2 -= rintf(s2);
                float ddx = s0 * box[0] + s1 * box[3] + s2 * box[6];
                float ddy = s0 * box[1] + s1 * box[4] + s2 * box[7];
                float ddz = s0 * box[2] + s1 * box[5] + s2 * box[8];
                float r2 = fmaf(ddx, ddx, fmaf(ddy, ddy, ddz * ddz));
                bool valid = (r2 < CUTOFF2) & (jg > i) & (jg < N);
                for (int k = 0; k < ne; k++) valid = valid & (ex[k] != jg);
                float r2m = valid ? r2 : 1.0f;
                float rinv = __builtin_amdgcn_rsqf(r2m);
                float r = r2m * rinv;
                float g = erfc_fast(ALPHA * r) * rinv;
                float qqm = valid ? qi * o.w : 0.0f;
                fsum = fmaf(qqm, g, fsum);
            }
        }
        e = (double)(COULOMB * fsum);

        // anchor tile: self-energy + exclusion corrections for atom i
        if (jb == ib) {
            const float inv_sqrt_pi = 0.5641895835477563f;
            float corr = -ALPHA * inv_sqrt_pi * qi * qi;
            for (int k = 0; k < ne; k++) {
                int j = ex[k];
                if (j < 0) continue;
                float4 o = pxq[j];
                float dx = xi - o.x, dy = yi - o.y, dz = zi - o.z;
                if (B.diag) {
                    dx -= rintf(dx * B.inv[0]) * box[0];
                    dy -= rintf(dy * B.inv[4]) * box[4];
                    dz -= rintf(dz * B.inv[8]) * box[8];
                } else {
                    float s0 = dx * B.inv[0] + dy * B.inv[3] + dz * B.inv[6];
                    float s1 = dx * B.inv[1] + dy * B.inv[4] + dz * B.inv[7];
                    float s2 = dx * B.inv[2] + dy * B.inv[5] + dz * B.inv[8];
                    s0 -= rintf(s0);
                    s1 -= rintf(s1);
                    s2 -= rintf(s2);
                    dx = s0 * box[0] + s1 * box[3] + s2 * box[6];
                    dy = s0 * box[1] + s1 * box[4] + s2 * box[7];
                    dz = s0 * box[2] + s1 * box[5] + s2 * box[8];
                }
                float r2 = dx * dx + dy * dy + dz * dz;
                if (r2 > 0.0f) {
                    float rinv = __builtin_amdgcn_rsqf(r2);
                    float r = r2 * rinv;
                    float erfv = 1.0f - erfc_fast(ALPHA * r);
                    corr += -0.5f * qi * o.w * erfv * rinv;
                }
            }
            e += (double)(COULOMB * corr);
        }
    }

    // block reduce -> acc slot; last finishing block sums slots -> out
    __syncthreads();
#pragma unroll
    for (int off = 32; off > 0; off >>= 1) e += __shfl_down(e, off, 64);
    if (ln == 0) wsum[wv] = e;
    __syncthreads();
    if (tid == 0) {
        double eb = wsum[0] + wsum[1] + wsum[2] + wsum[3];
        double old = atomicAdd(&acc[blockIdx.x & 15], eb);
        __asm__ volatile("" ::"v"(old) : "memory");  // acc-add acked before cnt
        unsigned prev = atomicAdd(cnt, 1u);
        if (prev == total - 1u) {
            double s = 0.0;
#pragma unroll
            for (int k = 0; k < 16; k++)
                s += __hip_atomic_load(&acc[k], __ATOMIC_RELAXED, __HIP_MEMORY_SCOPE_AGENT);
            out[0] = (float)s;
        }
    }
}

// ---------------------------------------------------------------- launch

extern "C" void kernel_launch(void* const* d_in, const int* in_sizes, int n_in,
                              void* d_out, int out_size, void* d_ws, size_t ws_size,
                              hipStream_t stream) {
    const float* pos = (const float*)d_in[0];
    const float* chg = (const float*)d_in[1];
    const float* box = (const float*)d_in[2];
    const int* excl = (const int*)d_in[3];
    int N = in_sizes[0] / 3;
    int E = in_sizes[3] / N;

    char* ws = (char*)d_ws;
    double* acc = (double*)ws;                // 16 doubles (zeroed)
    unsigned* cnt = (unsigned*)(ws + 128);    // 1 uint (zeroed)
    float* grid = (float*)(ws + 4096);        // 1 MB (zeroed)
    float2* bufA = (float2*)(ws + 0x110000);  // 2112*64 float2 ~ 1.06 MB
    float4* pxq = (float4*)(ws + 0x220000);   // 64 KB
    float* out = (float*)d_out;

    hipMemsetAsync(ws, 0, 4096 + 4 * (size_t)KG3, stream);  // acc + cnt + grid

    spread_kernel<<<(16 * N + 255) / 256, 256, 0, stream>>>(pos, chg, box, grid, pxq, N);
    dft2d_yz<<<KG, 512, 0, stream>>>(grid, bufA);
    dft_x_reduce<<<KG * MZK / 4, 256, 0, stream>>>(bufA, box, acc, cnt);

    int nib = (N + DIB - 1) / DIB;  // 16
    int njt = (N + DJT - 1) / DJT;  // 128
    int ratio = DIB / DJT;          // 8
    int nlive = 0;
    for (int ci = 0; ci < nib; ci++) nlive += njt - ratio * ci;  // 1088
    unsigned total = (unsigned)(KG * MZK / 4 + nlive);           // 528 + 1088
    direct_kernel<<<nlive, 256, 0, stream>>>(pxq, box, excl, N, E, nib, njt, acc, cnt, total,
                                             out);
}